// Round 1
// baseline (430.744 us; speedup 1.0000x reference)
//
#include <hip/hip_runtime.h>
#include <hip/hip_bf16.h>
#include <math.h>

#define N_TOK 2048
#define HIDDEN 2880
#define QKV_DIM 5120
#define LOG2E 1.44269504088896340736f

typedef __attribute__((ext_vector_type(8))) short short8;
typedef __attribute__((ext_vector_type(4))) float f32x4;

__device__ __forceinline__ float bf2f(unsigned short u) {
  union { unsigned int i; float f; } c; c.i = ((unsigned int)u) << 16; return c.f;
}
__device__ __forceinline__ unsigned short f2bf(float f) {
  union { float f; unsigned int i; } c; c.f = f;
  unsigned int i = c.i;
  return (unsigned short)((i + 0x7FFFu + ((i >> 16) & 1u)) >> 16);
}
__device__ __forceinline__ void gload16(const void* g, void* l) {
  __builtin_amdgcn_global_load_lds((const __attribute__((address_space(1))) void*)g,
                                   (__attribute__((address_space(3))) void*)l, 16, 0, 0);
}

// ---------------- RMSNorm (fp32 in -> bf16 out) ----------------
__global__ __launch_bounds__(256) void rmsnorm_kernel(
    const float* __restrict__ x, const float* __restrict__ scale,
    unsigned short* __restrict__ t)
{
  int row = blockIdx.x;
  const float* xr = x + (size_t)row * HIDDEN;
  float ss = 0.f;
  for (int i = threadIdx.x; i < HIDDEN / 4; i += 256) {
    float4 v = ((const float4*)xr)[i];
    ss += v.x * v.x + v.y * v.y + v.z * v.z + v.w * v.w;
  }
#pragma unroll
  for (int off = 32; off; off >>= 1) ss += __shfl_down(ss, off, 64);
  __shared__ float red[4];
  if ((threadIdx.x & 63) == 0) red[threadIdx.x >> 6] = ss;
  __syncthreads();
  float total = red[0] + red[1] + red[2] + red[3];
  float rinv = rsqrtf(total / (float)HIDDEN + 1e-5f);
  for (int i = threadIdx.x; i < HIDDEN / 4; i += 256) {
    float4 v = ((const float4*)xr)[i];
    float4 s4 = ((const float4*)scale)[i];
    union { unsigned short u[4]; uint2 p; } pk;
    pk.u[0] = f2bf(v.x * rinv * s4.x);
    pk.u[1] = f2bf(v.y * rinv * s4.y);
    pk.u[2] = f2bf(v.z * rinv * s4.z);
    pk.u[3] = f2bf(v.w * rinv * s4.w);
    *(uint2*)&t[(size_t)row * HIDDEN + i * 4] = pk.p;
  }
}

// ---------------- transpose + cast fp32[R][C] -> bf16[C][R] ----------------
__global__ __launch_bounds__(256) void transpose_cast(
    const float* __restrict__ in, unsigned short* __restrict__ out,
    int R, int C, int outStride)
{
  __shared__ float tile[32][33];
  int c0 = blockIdx.x * 32, r0 = blockIdx.y * 32;
  int tx = threadIdx.x & 31, ty = threadIdx.x >> 5;
#pragma unroll
  for (int rr = ty; rr < 32; rr += 8)
    tile[rr][tx] = in[(size_t)(r0 + rr) * C + c0 + tx];
  __syncthreads();
#pragma unroll
  for (int rr = ty; rr < 32; rr += 8)
    out[(size_t)(c0 + rr) * outStride + r0 + tx] = f2bf(tile[tx][rr]);
}

// ---------------- m97-style GEMM: C = A[M,K] * Bt[N,K]^T ----------------
// EPI==1: C bf16 = acc + bias           (qkv projection)
// EPI==2: C f32  = acc + bias + resid   (out projection + residual), col-guarded
template <int EPI>
__global__ __launch_bounds__(256) void gemm_bt(
    const unsigned short* __restrict__ A,
    const unsigned short* __restrict__ Bt,
    const float* __restrict__ bias,
    const float* __restrict__ resid,
    void* __restrict__ Cout,
    int K, int Ncols)
{
  __shared__ unsigned short As[128][64];
  __shared__ unsigned short Bs[128][64];
  const int tid = threadIdx.x;
  const int lane = tid & 63;
  const int w = tid >> 6;
  const int wr = (w >> 1) * 64;
  const int wc = (w & 1) * 64;
  const int row0 = blockIdx.y * 128;
  const int col0 = blockIdx.x * 128;
  const int fr = lane & 15, fq = lane >> 4;

  f32x4 acc[4][4];
#pragma unroll
  for (int m2 = 0; m2 < 4; ++m2)
#pragma unroll
    for (int n2 = 0; n2 < 4; ++n2) acc[m2][n2] = (f32x4)0.f;

  for (int kt = 0; kt < K; kt += 64) {
#pragma unroll
    for (int c = 0; c < 4; ++c) {
      int g = tid + 256 * c;
      int r = g >> 3, c16 = g & 7;
      gload16(A + (size_t)(row0 + r) * K + kt + c16 * 8, (unsigned short*)&As[0][0] + (size_t)g * 8);
      gload16(Bt + (size_t)(col0 + r) * K + kt + c16 * 8, (unsigned short*)&Bs[0][0] + (size_t)g * 8);
    }
    __syncthreads();
#pragma unroll
    for (int kk = 0; kk < 2; ++kk) {
      short8 a[4], b[4];
#pragma unroll
      for (int m2 = 0; m2 < 4; ++m2)
        a[m2] = *(const short8*)&As[wr + m2 * 16 + fr][kk * 32 + fq * 8];
#pragma unroll
      for (int n2 = 0; n2 < 4; ++n2)
        b[n2] = *(const short8*)&Bs[wc + n2 * 16 + fr][kk * 32 + fq * 8];
#pragma unroll
      for (int m2 = 0; m2 < 4; ++m2)
#pragma unroll
        for (int n2 = 0; n2 < 4; ++n2)
          acc[m2][n2] = __builtin_amdgcn_mfma_f32_16x16x32_bf16(a[m2], b[n2], acc[m2][n2], 0, 0, 0);
    }
    __syncthreads();
  }
#pragma unroll
  for (int m2 = 0; m2 < 4; ++m2) {
#pragma unroll
    for (int n2 = 0; n2 < 4; ++n2) {
      int colb = col0 + wc + n2 * 16 + fr;
#pragma unroll
      for (int r2 = 0; r2 < 4; ++r2) {
        int rowg = row0 + wr + m2 * 16 + fq * 4 + r2;
        float v = acc[m2][n2][r2];
        if (EPI == 1) {
          v += bias[colb];
          ((unsigned short*)Cout)[(size_t)rowg * Ncols + colb] = f2bf(v);
        } else {
          if (colb < Ncols) {
            v += bias[colb] + resid[(size_t)rowg * Ncols + colb];
            ((float*)Cout)[(size_t)rowg * Ncols + colb] = v;
          }
        }
      }
    }
  }
}

// ---------------- YaRN RoPE in-place on bf16 qkv (q + k regions) ----------------
__global__ __launch_bounds__(256) void rope_kernel(unsigned short* __restrict__ qkv)
{
  int token = blockIdx.y;
  int p = blockIdx.x * 256 + threadIdx.x;  // 72 heads * 32 pairs = 2304
  if (p >= 72 * 32) return;
  int h = p >> 5, j = p & 31;
  const float log_base = 11.9183905731f;   // ln(150000)
  float fj = (float)j;
  float extrap = expf(-log_base * fj * 0.03125f);   // 1/freq
  float interp = extrap * 0.03125f;                 // 1/(32*freq)
  const float low  = 32.f * logf(4096.f / (32.f * 6.283185307179586f)) / log_base;
  const float high = 32.f * logf(4096.f / 6.283185307179586f) / log_base;
  float ramp = (fj - low) / (high - low);
  float maskv = 1.f - fminf(fmaxf(ramp, 0.f), 1.f);
  float inv_freq = interp * (1.f - maskv) + extrap * maskv;
  float ang = (float)token * inv_freq;
  const float conc = 1.3465735903f;  // 0.1*ln(32)+1
  float s, c;
  sincosf(ang, &s, &c);
  c *= conc; s *= conc;
  size_t base = (size_t)token * QKV_DIM + h * 64 + j;
  float x1 = bf2f(qkv[base]), x2 = bf2f(qkv[base + 32]);
  qkv[base]      = f2bf(x1 * c - x2 * s);
  qkv[base + 32] = f2bf(x2 * c + x1 * s);
}

// ---------------- sliding-window attention with sinks (SIMT) ----------------
// block: (qb: 32 queries) x (kvh); 256 threads = 32 queries * 8 q_mult heads
__global__ __launch_bounds__(256) void attn_kernel(
    const unsigned short* __restrict__ qkv, const float* __restrict__ sinks,
    unsigned short* __restrict__ attn)
{
  __shared__ float Ks[160][64];
  __shared__ float Vs[160][64];
  const int tid = threadIdx.x;
  const int qb = blockIdx.x, kvh = blockIdx.y;
  const int q0 = qb * 32;
  const int kbase = q0 - 127;

  // stage K/V window (slots 0..159 -> keys kbase..kbase+159), bf16 -> f32
  for (int e = tid; e < 160 * 32; e += 256) {
    int s = e >> 5, d2 = (e & 31) * 2;
    int j = kbase + s;
    float a = 0.f, b = 0.f, va = 0.f, vb = 0.f;
    if (j >= 0 && j < N_TOK) {
      const unsigned short* kp = qkv + (size_t)j * QKV_DIM + 4096 + kvh * 64 + d2;
      ushort2 ku = *(const ushort2*)kp;
      a = bf2f(ku.x); b = bf2f(ku.y);
      const unsigned short* vp = qkv + (size_t)j * QKV_DIM + 4608 + kvh * 64 + d2;
      ushort2 vu = *(const ushort2*)vp;
      va = bf2f(vu.x); vb = bf2f(vu.y);
    }
    *(float2*)&Ks[s][d2] = make_float2(a, b);
    *(float2*)&Vs[s][d2] = make_float2(va, vb);
  }
  __syncthreads();

  const int lq = tid & 31;    // query within block
  const int qm = tid >> 5;    // q_mult head
  const int i = q0 + lq;
  const int head = kvh * 8 + qm;
  const float SC = 0.125f * LOG2E;  // sm_scale * log2(e)

  float qreg[64];
  const unsigned short* qp = qkv + (size_t)i * QKV_DIM + head * 64;
#pragma unroll
  for (int d = 0; d < 64; d += 2) {
    ushort2 u = *(const ushort2*)(qp + d);
    qreg[d] = bf2f(u.x) * SC; qreg[d + 1] = bf2f(u.y) * SC;
  }
  float m = -1e30f, l = 0.f;
  float out[64];
#pragma unroll
  for (int d = 0; d < 64; ++d) out[d] = 0.f;

  int s0 = kbase < 0 ? -kbase : 0;
  for (int s = s0; s <= 158; ++s) {
    float a0 = 0.f, a1 = 0.f, a2 = 0.f, a3 = 0.f;
#pragma unroll
    for (int d = 0; d < 64; d += 4) {
      float4 kv = *(const float4*)&Ks[s][d];
      a0 += qreg[d] * kv.x; a1 += qreg[d + 1] * kv.y;
      a2 += qreg[d + 2] * kv.z; a3 += qreg[d + 3] * kv.w;
    }
    float sc = (a0 + a1) + (a2 + a3);
    bool valid = (s >= lq) && (s <= lq + 127);
    if (valid) {
      float dd = sc - m;
      if (dd > 8.f) {            // rare rescale (defer-max)
        float r = exp2f(-dd);
        l *= r;
#pragma unroll
        for (int d = 0; d < 64; ++d) out[d] *= r;
        m = sc;
      }
      float p = exp2f(sc - m);
      l += p;
#pragma unroll
      for (int d = 0; d < 64; d += 4) {
        float4 vv = *(const float4*)&Vs[s][d];
        out[d] += p * vv.x; out[d + 1] += p * vv.y;
        out[d + 2] += p * vv.z; out[d + 3] += p * vv.w;
      }
    }
  }
  // sink contributes only to the denominator
  float sk = sinks[head] * LOG2E;
  float dd = sk - m;
  if (dd > 0.f) {
    float r = exp2f(-dd);
    l = l * r + 1.f;
#pragma unroll
    for (int d = 0; d < 64; ++d) out[d] *= r;
  } else {
    l += exp2f(dd);
  }
  float inv = 1.f / l;
  unsigned short* op = attn + (size_t)i * 4096 + head * 64;
#pragma unroll
  for (int d = 0; d < 64; d += 2) {
    unsigned int pk2 = (unsigned int)f2bf(out[d] * inv) |
                       ((unsigned int)f2bf(out[d + 1] * inv) << 16);
    *(unsigned int*)(op + d) = pk2;
  }
}

extern "C" void kernel_launch(void* const* d_in, const int* in_sizes, int n_in,
                              void* d_out, int out_size, void* d_ws, size_t ws_size,
                              hipStream_t stream)
{
  const float* x      = (const float*)d_in[0];
  const float* nscale = (const float*)d_in[1];
  const float* w_qkv  = (const float*)d_in[2];
  const float* b_qkv  = (const float*)d_in[3];
  const float* sinks  = (const float*)d_in[4];
  const float* w_out  = (const float*)d_in[5];
  const float* b_out  = (const float*)d_in[6];

  char* ws = (char*)d_ws;
  unsigned short* t_bf  = (unsigned short*)(ws);                 // [2048][2880] bf16
  unsigned short* wqkvT = (unsigned short*)(ws + 11796480);      // [5120][2880] bf16
  unsigned short* qkv   = (unsigned short*)(ws + 41287680);      // [2048][5120] bf16
  unsigned short* attn  = (unsigned short*)(ws + 62259200);      // [2048][4096] bf16
  unsigned short* woutT = (unsigned short*)(ws + 79036416);      // [2944 pad][4096] bf16

  rmsnorm_kernel<<<N_TOK, 256, 0, stream>>>(x, nscale, t_bf);
  transpose_cast<<<dim3(5120 / 32, 2880 / 32), 256, 0, stream>>>(w_qkv, wqkvT, 2880, 5120, 2880);
  transpose_cast<<<dim3(2880 / 32, 4096 / 32), 256, 0, stream>>>(w_out, woutT, 4096, 2880, 4096);
  gemm_bt<1><<<dim3(40, 16), 256, 0, stream>>>(t_bf, wqkvT, b_qkv, nullptr, (void*)qkv, 2880, 5120);
  rope_kernel<<<dim3(9, N_TOK), 256, 0, stream>>>(qkv);
  attn_kernel<<<dim3(64, 8), 256, 0, stream>>>(qkv, sinks, attn);
  gemm_bt<2><<<dim3(23, 16), 256, 0, stream>>>(attn, woutT, b_out, x, d_out, 4096, 2880);
}

// Round 2
// 308.066 us; speedup vs baseline: 1.3982x; 1.3982x over previous
//
#include <hip/hip_runtime.h>
#include <hip/hip_bf16.h>
#include <math.h>

#define N_TOK 2048
#define HIDDEN 2880
#define QKV_DIM 5120
#define LOG2E 1.44269504088896340736f

typedef __attribute__((ext_vector_type(8))) short short8;
typedef __attribute__((ext_vector_type(4))) float f32x4;
typedef __attribute__((ext_vector_type(16))) float f32x16;

__device__ __forceinline__ float bf2f(unsigned short u) {
  union { unsigned int i; float f; } c; c.i = ((unsigned int)u) << 16; return c.f;
}
__device__ __forceinline__ unsigned short f2bf(float f) {
  union { float f; unsigned int i; } c; c.f = f;
  unsigned int i = c.i;
  return (unsigned short)((i + 0x7FFFu + ((i >> 16) & 1u)) >> 16);
}
__device__ __forceinline__ void gload16(const void* g, void* l) {
  __builtin_amdgcn_global_load_lds((const __attribute__((address_space(1))) void*)g,
                                   (__attribute__((address_space(3))) void*)l, 16, 0, 0);
}

// ---------------- RMSNorm (fp32 in -> bf16 out) ----------------
__global__ __launch_bounds__(256) void rmsnorm_kernel(
    const float* __restrict__ x, const float* __restrict__ scale,
    unsigned short* __restrict__ t)
{
  int row = blockIdx.x;
  const float* xr = x + (size_t)row * HIDDEN;
  float ss = 0.f;
  for (int i = threadIdx.x; i < HIDDEN / 4; i += 256) {
    float4 v = ((const float4*)xr)[i];
    ss += v.x * v.x + v.y * v.y + v.z * v.z + v.w * v.w;
  }
#pragma unroll
  for (int off = 32; off; off >>= 1) ss += __shfl_down(ss, off, 64);
  __shared__ float red[4];
  if ((threadIdx.x & 63) == 0) red[threadIdx.x >> 6] = ss;
  __syncthreads();
  float total = red[0] + red[1] + red[2] + red[3];
  float rinv = rsqrtf(total / (float)HIDDEN + 1e-5f);
  for (int i = threadIdx.x; i < HIDDEN / 4; i += 256) {
    float4 v = ((const float4*)xr)[i];
    float4 s4 = ((const float4*)scale)[i];
    union { unsigned short u[4]; uint2 p; } pk;
    pk.u[0] = f2bf(v.x * rinv * s4.x);
    pk.u[1] = f2bf(v.y * rinv * s4.y);
    pk.u[2] = f2bf(v.z * rinv * s4.z);
    pk.u[3] = f2bf(v.w * rinv * s4.w);
    *(uint2*)&t[(size_t)row * HIDDEN + i * 4] = pk.p;
  }
}

// ---------------- transpose + cast fp32[R][C] -> bf16[C][R] ----------------
__global__ __launch_bounds__(256) void transpose_cast(
    const float* __restrict__ in, unsigned short* __restrict__ out,
    int R, int C, int outStride)
{
  __shared__ float tile[32][33];
  int c0 = blockIdx.x * 32, r0 = blockIdx.y * 32;
  int tx = threadIdx.x & 31, ty = threadIdx.x >> 5;
#pragma unroll
  for (int rr = ty; rr < 32; rr += 8)
    tile[rr][tx] = in[(size_t)(r0 + rr) * C + c0 + tx];
  __syncthreads();
#pragma unroll
  for (int rr = ty; rr < 32; rr += 8)
    out[(size_t)(c0 + rr) * outStride + r0 + tx] = f2bf(tile[tx][rr]);
}

// ---------------- m97-style GEMM: C = A[M,K] * Bt[N,K]^T ----------------
template <int EPI>
__global__ __launch_bounds__(256) void gemm_bt(
    const unsigned short* __restrict__ A,
    const unsigned short* __restrict__ Bt,
    const float* __restrict__ bias,
    const float* __restrict__ resid,
    void* __restrict__ Cout,
    int K, int Ncols)
{
  __shared__ unsigned short As[128][64];
  __shared__ unsigned short Bs[128][64];
  const int tid = threadIdx.x;
  const int lane = tid & 63;
  const int w = tid >> 6;
  const int wr = (w >> 1) * 64;
  const int wc = (w & 1) * 64;
  const int row0 = blockIdx.y * 128;
  const int col0 = blockIdx.x * 128;
  const int fr = lane & 15, fq = lane >> 4;

  f32x4 acc[4][4];
#pragma unroll
  for (int m2 = 0; m2 < 4; ++m2)
#pragma unroll
    for (int n2 = 0; n2 < 4; ++n2) acc[m2][n2] = (f32x4)0.f;

  for (int kt = 0; kt < K; kt += 64) {
#pragma unroll
    for (int c = 0; c < 4; ++c) {
      int g = tid + 256 * c;
      int r = g >> 3, c16 = g & 7;
      gload16(A + (size_t)(row0 + r) * K + kt + c16 * 8, (unsigned short*)&As[0][0] + (size_t)g * 8);
      gload16(Bt + (size_t)(col0 + r) * K + kt + c16 * 8, (unsigned short*)&Bs[0][0] + (size_t)g * 8);
    }
    __syncthreads();
#pragma unroll
    for (int kk = 0; kk < 2; ++kk) {
      short8 a[4], b[4];
#pragma unroll
      for (int m2 = 0; m2 < 4; ++m2)
        a[m2] = *(const short8*)&As[wr + m2 * 16 + fr][kk * 32 + fq * 8];
#pragma unroll
      for (int n2 = 0; n2 < 4; ++n2)
        b[n2] = *(const short8*)&Bs[wc + n2 * 16 + fr][kk * 32 + fq * 8];
#pragma unroll
      for (int m2 = 0; m2 < 4; ++m2)
#pragma unroll
        for (int n2 = 0; n2 < 4; ++n2)
          acc[m2][n2] = __builtin_amdgcn_mfma_f32_16x16x32_bf16(a[m2], b[n2], acc[m2][n2], 0, 0, 0);
    }
    __syncthreads();
  }
#pragma unroll
  for (int m2 = 0; m2 < 4; ++m2) {
#pragma unroll
    for (int n2 = 0; n2 < 4; ++n2) {
      int colb = col0 + wc + n2 * 16 + fr;
#pragma unroll
      for (int r2 = 0; r2 < 4; ++r2) {
        int rowg = row0 + wr + m2 * 16 + fq * 4 + r2;
        float v = acc[m2][n2][r2];
        if (EPI == 1) {
          v += bias[colb];
          ((unsigned short*)Cout)[(size_t)rowg * Ncols + colb] = f2bf(v);
        } else {
          if (colb < Ncols) {
            v += bias[colb] + resid[(size_t)rowg * Ncols + colb];
            ((float*)Cout)[(size_t)rowg * Ncols + colb] = v;
          }
        }
      }
    }
  }
}

// ---------------- YaRN RoPE in-place on bf16 qkv (q + k regions) ----------------
__global__ __launch_bounds__(256) void rope_kernel(unsigned short* __restrict__ qkv)
{
  int token = blockIdx.y;
  int p = blockIdx.x * 256 + threadIdx.x;  // 72 heads * 32 pairs = 2304
  if (p >= 72 * 32) return;
  int h = p >> 5, j = p & 31;
  const float log_base = 11.9183905731f;   // ln(150000)
  float fj = (float)j;
  float extrap = expf(-log_base * fj * 0.03125f);   // 1/freq
  float interp = extrap * 0.03125f;                 // 1/(32*freq)
  const float low  = 32.f * logf(4096.f / (32.f * 6.283185307179586f)) / log_base;
  const float high = 32.f * logf(4096.f / 6.283185307179586f) / log_base;
  float ramp = (fj - low) / (high - low);
  float maskv = 1.f - fminf(fmaxf(ramp, 0.f), 1.f);
  float inv_freq = interp * (1.f - maskv) + extrap * maskv;
  float ang = (float)token * inv_freq;
  const float conc = 1.3465735903f;  // 0.1*ln(32)+1
  float s, c;
  sincosf(ang, &s, &c);
  c *= conc; s *= conc;
  size_t base = (size_t)token * QKV_DIM + h * 64 + j;
  float x1 = bf2f(qkv[base]), x2 = bf2f(qkv[base + 32]);
  qkv[base]      = f2bf(x1 * c - x2 * s);
  qkv[base + 32] = f2bf(x2 * c + x1 * s);
}

// ---------------- MFMA sliding-window attention with sinks ----------------
// block = (qb: 32 queries, kvh). 512 threads = 8 waves; wave w = q-head w.
// S^T = mfma(K, Q): lane owns q-row (col=lane&31); keys in regs.
// O^T = mfma(V^T, P^T): same col=q layout -> lane-local online softmax.
__global__ __launch_bounds__(512) void attn_kernel(
    const unsigned short* __restrict__ qkv, const float* __restrict__ sinks,
    unsigned short* __restrict__ attn)
{
  __shared__ unsigned short Ks[160 * 64];   // [key r][d], 8x16B slots, slot ^= (r&7)
  __shared__ unsigned short Vt[64 * 192];   // [d][key], 24x16B slots, slot ^= (d&7)
  const int tid  = threadIdx.x;
  const int lane = tid & 63;
  const int w    = tid >> 6;
  const int qb = blockIdx.x, kvh = blockIdx.y;
  const int q0 = qb * 32;
  const int kb = q0 - 128;                  // aligned staging base (5 tiles of 32)
  const int h  = lane >> 5;                 // lane half
  const int ql = lane & 31;

  // ---- stage K via global_load_lds (linear LDS dest, pre-swizzled global src) ----
  for (int it = w; it < 20; it += 8) {
    int r = it * 8 + (lane >> 3);
    int s = lane & 7;
    int j = kb + r; if (j < 0) j = 0;
    const unsigned short* src =
        qkv + (size_t)j * QKV_DIM + 4096 + kvh * 64 + ((s ^ (r & 7)) * 8);
    gload16(src, &Ks[r * 64 + s * 8]);
  }
  // ---- stage V transposed into Vt ----
  for (int c = tid; c < 2560; c += 512) {
    int jl = c >> 4;                // 0..159
    int d4 = (c & 15) * 4;          // 0..60
    int j = kb + jl; if (j < 0) j = 0;
    ushort4 v4 = *(const ushort4*)&qkv[(size_t)j * QKV_DIM + 4608 + kvh * 64 + d4];
    const unsigned short* pv = (const unsigned short*)&v4;
#pragma unroll
    for (int t = 0; t < 4; ++t) {
      int d = d4 + t;
      int slot = (jl >> 3) ^ (d & 7);
      Vt[d * 192 + slot * 8 + (jl & 7)] = pv[t];
    }
  }
  // ---- Q fragments (B-operand: lane = q row ql, k-slice = ks*16 + h*8) ----
  const int head = kvh * 8 + w;
  const int i_q = q0 + ql;
  short8 qf[4];
  {
    const unsigned short* qp = qkv + (size_t)i_q * QKV_DIM + head * 64 + h * 8;
#pragma unroll
    for (int ks = 0; ks < 4; ++ks) qf[ks] = *(const short8*)(qp + ks * 16);
  }
  __syncthreads();

  const float SC = 0.125f * LOG2E;
  f32x16 oacc0 = (f32x16)(0.f), oacc1 = (f32x16)(0.f);
  float m = -1e30f, l = 0.f;

  const int tstart = qb < 4 ? 4 - qb : 0;
  for (int tt = tstart; tt < 5; ++tt) {
    const int j0 = kb + tt * 32;
    // ---- S^T = K * Q^T (A = K rows, B = Q) ----
    f32x16 sacc = (f32x16)(0.f);
    const int kr = tt * 32 + ql;
#pragma unroll
    for (int ks = 0; ks < 4; ++ks) {
      short8 kf = *(const short8*)&Ks[kr * 64 + (((ks * 2 + h) ^ (kr & 7)) * 8)];
      sacc = __builtin_amdgcn_mfma_f32_32x32x16_bf16(kf, qf[ks], sacc, 0, 0, 0);
    }
    // ---- mask + online softmax (lane-local for q-row ql) ----
    float sc16[16];
    float mt = -1e30f * 1e8f;  // -inf stand-in start
    mt = -INFINITY;
#pragma unroll
    for (int e = 0; e < 16; ++e) {
      int kk = (e & 3) + 8 * (e >> 2) + 4 * h;
      int j = j0 + kk;
      float s2 = sacc[e] * SC;
      bool valid = (j <= i_q) && (j > i_q - 128);
      s2 = valid ? s2 : -INFINITY;
      sc16[e] = s2;
      mt = fmaxf(mt, s2);
    }
    mt = fmaxf(mt, __shfl_xor(mt, 32));
    float mnew = fmaxf(m, mt);          // finite: m starts at -1e30
    float r = exp2f(m - mnew);
    l *= r;
    oacc0 *= r;
    oacc1 *= r;
    m = mnew;
    unsigned int wpk[8];
    float ls = 0.f;
#pragma unroll
    for (int e2 = 0; e2 < 8; ++e2) {
      float plo = exp2f(sc16[2 * e2]     - m);
      float phi = exp2f(sc16[2 * e2 + 1] - m);
      ls += plo + phi;
      asm("v_cvt_pk_bf16_f32 %0, %1, %2" : "=v"(wpk[e2]) : "v"(plo), "v"(phi));
    }
    l += ls;
    // ---- PV: O^T += V^T * P^T ----
#pragma unroll
    for (int m16 = 0; m16 < 2; ++m16) {
      int go = 2 * m16 + h;       // own group used
      int gs = 2 * m16 + 1 - h;   // group sent to partner
      unsigned int x0 = (unsigned int)__shfl_xor((int)wpk[2 * gs],     32);
      unsigned int x1 = (unsigned int)__shfl_xor((int)wpk[2 * gs + 1], 32);
      union { unsigned int u[4]; short8 s; } bu;
      bu.u[0] = h ? x0 : wpk[2 * go];
      bu.u[1] = h ? x1 : wpk[2 * go + 1];
      bu.u[2] = h ? wpk[2 * go]     : x0;
      bu.u[3] = h ? wpk[2 * go + 1] : x1;
      short8 bfrag = bu.s;
#pragma unroll
      for (int dt = 0; dt < 2; ++dt) {
        int d = dt * 32 + ql;
        int slot = (tt * 4 + m16 * 2 + h) ^ (d & 7);
        short8 vf = *(const short8*)&Vt[d * 192 + slot * 8];
        if (dt == 0)
          oacc0 = __builtin_amdgcn_mfma_f32_32x32x16_bf16(vf, bfrag, oacc0, 0, 0, 0);
        else
          oacc1 = __builtin_amdgcn_mfma_f32_32x32x16_bf16(vf, bfrag, oacc1, 0, 0, 0);
      }
    }
  }
  // ---- finalize: add sink to denominator, normalize, write O ----
  float lt = l + __shfl_xor(l, 32);
  lt += exp2f(sinks[head] * LOG2E - m);
  float inv = 1.f / lt;
  unsigned short* op = attn + (size_t)i_q * 4096 + head * 64;
#pragma unroll
  for (int dt = 0; dt < 2; ++dt) {
#pragma unroll
    for (int g = 0; g < 4; ++g) {
      float f0, f1, f2, f3;
      if (dt == 0) {
        f0 = oacc0[4 * g]; f1 = oacc0[4 * g + 1]; f2 = oacc0[4 * g + 2]; f3 = oacc0[4 * g + 3];
      } else {
        f0 = oacc1[4 * g]; f1 = oacc1[4 * g + 1]; f2 = oacc1[4 * g + 2]; f3 = oacc1[4 * g + 3];
      }
      unsigned int u0, u1;
      asm("v_cvt_pk_bf16_f32 %0, %1, %2" : "=v"(u0) : "v"(f0 * inv), "v"(f1 * inv));
      asm("v_cvt_pk_bf16_f32 %0, %1, %2" : "=v"(u1) : "v"(f2 * inv), "v"(f3 * inv));
      int d = dt * 32 + 8 * g + 4 * h;
      uint2 pr; pr.x = u0; pr.y = u1;
      *(uint2*)(op + d) = pr;
    }
  }
}

extern "C" void kernel_launch(void* const* d_in, const int* in_sizes, int n_in,
                              void* d_out, int out_size, void* d_ws, size_t ws_size,
                              hipStream_t stream)
{
  const float* x      = (const float*)d_in[0];
  const float* nscale = (const float*)d_in[1];
  const float* w_qkv  = (const float*)d_in[2];
  const float* b_qkv  = (const float*)d_in[3];
  const float* sinks  = (const float*)d_in[4];
  const float* w_out  = (const float*)d_in[5];
  const float* b_out  = (const float*)d_in[6];

  char* ws = (char*)d_ws;
  unsigned short* t_bf  = (unsigned short*)(ws);                 // [2048][2880] bf16
  unsigned short* wqkvT = (unsigned short*)(ws + 11796480);      // [5120][2880] bf16
  unsigned short* qkv   = (unsigned short*)(ws + 41287680);      // [2048][5120] bf16
  unsigned short* attn  = (unsigned short*)(ws + 62259200);      // [2048][4096] bf16
  unsigned short* woutT = (unsigned short*)(ws + 79036416);      // [4096][2880->stride 4096] bf16

  rmsnorm_kernel<<<N_TOK, 256, 0, stream>>>(x, nscale, t_bf);
  transpose_cast<<<dim3(5120 / 32, 2880 / 32), 256, 0, stream>>>(w_qkv, wqkvT, 2880, 5120, 2880);
  transpose_cast<<<dim3(2880 / 32, 4096 / 32), 256, 0, stream>>>(w_out, woutT, 4096, 2880, 4096);
  gemm_bt<1><<<dim3(40, 16), 256, 0, stream>>>(t_bf, wqkvT, b_qkv, nullptr, (void*)qkv, 2880, 5120);
  rope_kernel<<<dim3(9, N_TOK), 256, 0, stream>>>(qkv);
  attn_kernel<<<dim3(64, 8), 512, 0, stream>>>(qkv, sinks, attn);
  gemm_bt<2><<<dim3(23, 16), 256, 0, stream>>>(attn, woutT, b_out, x, d_out, 4096, 2880);
}

// Round 3
// 299.987 us; speedup vs baseline: 1.4359x; 1.0269x over previous
//
#include <hip/hip_runtime.h>
#include <hip/hip_bf16.h>
#include <math.h>

#define N_TOK 2048
#define HIDDEN 2880
#define QKV_DIM 5120
#define LOG2E 1.44269504088896340736f

typedef __attribute__((ext_vector_type(8))) short short8;
typedef __attribute__((ext_vector_type(4))) float f32x4;
typedef __attribute__((ext_vector_type(16))) float f32x16;

__device__ __forceinline__ float bf2f(unsigned short u) {
  union { unsigned int i; float f; } c; c.i = ((unsigned int)u) << 16; return c.f;
}
__device__ __forceinline__ unsigned short f2bf(float f) {
  union { float f; unsigned int i; } c; c.f = f;
  unsigned int i = c.i;
  return (unsigned short)((i + 0x7FFFu + ((i >> 16) & 1u)) >> 16);
}
__device__ __forceinline__ void gload16(const void* g, void* l) {
  __builtin_amdgcn_global_load_lds((const __attribute__((address_space(1))) void*)g,
                                   (__attribute__((address_space(3))) void*)l, 16, 0, 0);
}

// ---------------- RMSNorm (fp32 in -> bf16 out) ----------------
__global__ __launch_bounds__(256) void rmsnorm_kernel(
    const float* __restrict__ x, const float* __restrict__ scale,
    unsigned short* __restrict__ t)
{
  int row = blockIdx.x;
  const float* xr = x + (size_t)row * HIDDEN;
  float ss = 0.f;
  for (int i = threadIdx.x; i < HIDDEN / 4; i += 256) {
    float4 v = ((const float4*)xr)[i];
    ss += v.x * v.x + v.y * v.y + v.z * v.z + v.w * v.w;
  }
#pragma unroll
  for (int off = 32; off; off >>= 1) ss += __shfl_down(ss, off, 64);
  __shared__ float red[4];
  if ((threadIdx.x & 63) == 0) red[threadIdx.x >> 6] = ss;
  __syncthreads();
  float total = red[0] + red[1] + red[2] + red[3];
  float rinv = rsqrtf(total / (float)HIDDEN + 1e-5f);
  for (int i = threadIdx.x; i < HIDDEN / 4; i += 256) {
    float4 v = ((const float4*)xr)[i];
    float4 s4 = ((const float4*)scale)[i];
    union { unsigned short u[4]; uint2 p; } pk;
    pk.u[0] = f2bf(v.x * rinv * s4.x);
    pk.u[1] = f2bf(v.y * rinv * s4.y);
    pk.u[2] = f2bf(v.z * rinv * s4.z);
    pk.u[3] = f2bf(v.w * rinv * s4.w);
    *(uint2*)&t[(size_t)row * HIDDEN + i * 4] = pk.p;
  }
}

// ---------------- transpose + cast fp32[R][C] -> bf16[C][R] ----------------
__global__ __launch_bounds__(256) void transpose_cast(
    const float* __restrict__ in, unsigned short* __restrict__ out,
    int R, int C, int outStride)
{
  __shared__ float tile[32][33];
  int c0 = blockIdx.x * 32, r0 = blockIdx.y * 32;
  int tx = threadIdx.x & 31, ty = threadIdx.x >> 5;
#pragma unroll
  for (int rr = ty; rr < 32; rr += 8)
    tile[rr][tx] = in[(size_t)(r0 + rr) * C + c0 + tx];
  __syncthreads();
#pragma unroll
  for (int rr = ty; rr < 32; rr += 8)
    out[(size_t)(c0 + rr) * outStride + r0 + tx] = f2bf(tile[tx][rr]);
}

// ---------------- 256x256 8-phase GEMM: C = A[M,K] * Bt[N,K]^T ----------------
// 512 threads = 8 waves (2M x 4N), BK=64, 128 KiB LDS double-buffer.
// LDS per operand-buffer: [kk(2)][row(256)][32 cols], row=64B, 16B unit u
// swizzled u_phys = u_logical ^ (row&3). Staged via global_load_lds with
// pre-swizzled global source (linear LDS dest). Counted vmcnt(4) waits.
template <int EPI>
__global__ __launch_bounds__(512, 2) void gemm8(
    const unsigned short* __restrict__ A,
    const unsigned short* __restrict__ Bt,
    const float* __restrict__ bias,
    const float* __restrict__ resid,
    void* __restrict__ Cout,
    int K, int Ncols)
{
  __shared__ char smem_[131072];
  const int tid = threadIdx.x;
  const int lane = tid & 63;
  const int w = tid >> 6;
  const int fr = lane & 15, fq = lane >> 4;
  const int wr = w >> 2, wc = w & 3;

  // bijective XCD swizzle (nwg % 8 == 0)
  const int nwg = gridDim.x;
  const int cpx = nwg >> 3;
  const int wg = (blockIdx.x & 7) * cpx + (blockIdx.x >> 3);
  const int by = wg & 7, bx = wg >> 3;
  const int row0 = by * 256, col0 = bx * 256;

  // ---- staging address precompute (8 chunks/K-tile; c: 0,1=Bkk0 2,3=Akk0 4,5=Bkk1 6,7=Akk1)
  const unsigned short* gsrc[8];
  int ldsoff[8];
  {
    const int rloc = w * 16 + (lane >> 2);            // + (c&1)*128
    const int u2s = (lane & 3) ^ ((lane >> 2) & 3);   // logical u for this lane's slot
#pragma unroll
    for (int c = 0; c < 8; ++c) {
      const int isA = (c == 2 || c == 3 || c == 6 || c == 7);
      const int kb = c >> 2;
      const int r = (c & 1) * 128 + rloc;
      const int gc = kb * 32 + u2s * 8;
      gsrc[c] = isA ? (A + (size_t)(row0 + r) * K + gc)
                    : (Bt + (size_t)(col0 + r) * K + gc);
      ldsoff[c] = (isA ? 0 : 32768) + kb * 16384 + (c & 1) * 8192 + w * 1024 + lane * 16;
    }
  }
  // ---- ds_read offsets (physical u = fq ^ (row&3), row&3 == fr&3)
  const int urd = (fq ^ (fr & 3)) * 16;
  const int aoff = (wr * 128 + fr) * 64 + urd;
  const int boff = 32768 + (wc * 64 + fr) * 64 + urd;

  f32x4 acc[8][4];
#pragma unroll
  for (int mf = 0; mf < 8; ++mf)
#pragma unroll
    for (int nf = 0; nf < 4; ++nf) acc[mf][nf] = (f32x4)0.f;

  const int NT = K >> 6;

#define ISSUE(c) gload16(gsrc[c] + ktn, smem_ + nbufo + ldsoff[c])
#define RD_A(mf, kk) (*(const short8*)(smem_ + bufo + (kk)*16384 + (mf)*1024 + aoff))
#define RD_B(nf, kk) (*(const short8*)(smem_ + bufo + (kk)*16384 + (nf)*1024 + boff))
#define MM(mf, ar) \
  acc[mf][0] = __builtin_amdgcn_mfma_f32_16x16x32_bf16(ar, b0, acc[mf][0], 0, 0, 0); \
  acc[mf][1] = __builtin_amdgcn_mfma_f32_16x16x32_bf16(ar, b1, acc[mf][1], 0, 0, 0); \
  acc[mf][2] = __builtin_amdgcn_mfma_f32_16x16x32_bf16(ar, b2, acc[mf][2], 0, 0, 0); \
  acc[mf][3] = __builtin_amdgcn_mfma_f32_16x16x32_bf16(ar, b3, acc[mf][3], 0, 0, 0);

  // prologue: stage tile 0 into buffer 0
  {
    const int ktn = 0, nbufo = 0;
#pragma unroll
    for (int c = 0; c < 8; ++c) gload16(gsrc[c] + ktn, smem_ + nbufo + ldsoff[c]);
  }

  for (int t = 0; t < NT; ++t) {
    const int bufo = (t & 1) * 65536;
    const int nbufo = bufo ^ 65536;
    const int ktn = (t + 1) * 64;
    const bool pref = (t + 1) < NT;

    // checkpoint A: chunks 0-3 of this tile landed (4 newest may fly)
    asm volatile("s_waitcnt vmcnt(4)" ::: "memory");
    __builtin_amdgcn_s_barrier();

    short8 a0, a1, a2, a3, b0, b1, b2, b3;
    // ---- phase 0: mf0-3 x kk0 ----
    a0 = RD_A(0, 0); a1 = RD_A(1, 0); a2 = RD_A(2, 0); a3 = RD_A(3, 0);
    b0 = RD_B(0, 0); b1 = RD_B(1, 0); b2 = RD_B(2, 0); b3 = RD_B(3, 0);
    if (pref) { ISSUE(0); ISSUE(1); }
    __builtin_amdgcn_s_barrier();
    __builtin_amdgcn_s_setprio(1);
    MM(0, a0) MM(1, a1) MM(2, a2) MM(3, a3)
    __builtin_amdgcn_s_setprio(0);
    __builtin_amdgcn_s_barrier();
    // ---- phase 1: mf4-7 x kk0 ----
    a0 = RD_A(4, 0); a1 = RD_A(5, 0); a2 = RD_A(6, 0); a3 = RD_A(7, 0);
    if (pref) { ISSUE(2); ISSUE(3); }
    __builtin_amdgcn_s_barrier();
    __builtin_amdgcn_s_setprio(1);
    MM(4, a0) MM(5, a1) MM(6, a2) MM(7, a3)
    __builtin_amdgcn_s_setprio(0);
    // checkpoint B: chunks 4-7 of this tile landed
    if (pref) asm volatile("s_waitcnt vmcnt(4)" ::: "memory");
    else      asm volatile("s_waitcnt vmcnt(0)" ::: "memory");
    __builtin_amdgcn_s_barrier();
    // ---- phase 2: mf0-3 x kk1 ----
    a0 = RD_A(0, 1); a1 = RD_A(1, 1); a2 = RD_A(2, 1); a3 = RD_A(3, 1);
    b0 = RD_B(0, 1); b1 = RD_B(1, 1); b2 = RD_B(2, 1); b3 = RD_B(3, 1);
    if (pref) { ISSUE(4); ISSUE(5); }
    __builtin_amdgcn_s_barrier();
    __builtin_amdgcn_s_setprio(1);
    MM(0, a0) MM(1, a1) MM(2, a2) MM(3, a3)
    __builtin_amdgcn_s_setprio(0);
    __builtin_amdgcn_s_barrier();
    // ---- phase 3: mf4-7 x kk1 ----
    a0 = RD_A(4, 1); a1 = RD_A(5, 1); a2 = RD_A(6, 1); a3 = RD_A(7, 1);
    if (pref) { ISSUE(6); ISSUE(7); }
    __builtin_amdgcn_s_barrier();
    __builtin_amdgcn_s_setprio(1);
    MM(4, a0) MM(5, a1) MM(6, a2) MM(7, a3)
    __builtin_amdgcn_s_setprio(0);
    // tail barrier folded into next loop-top checkpoint
  }
#undef ISSUE
#undef RD_A
#undef RD_B
#undef MM

  // ---- epilogue ----
#pragma unroll
  for (int mf = 0; mf < 8; ++mf) {
#pragma unroll
    for (int nf = 0; nf < 4; ++nf) {
      const int colb = col0 + wc * 64 + nf * 16 + fr;
      const int rowb = row0 + wr * 128 + mf * 16 + fq * 4;
      if (EPI == 1) {
        const float bs = bias[colb];
#pragma unroll
        for (int j = 0; j < 4; ++j)
          ((unsigned short*)Cout)[(size_t)(rowb + j) * Ncols + colb] =
              f2bf(acc[mf][nf][j] + bs);
      } else {
        if (colb < Ncols) {
          const float bs = bias[colb];
#pragma unroll
          for (int j = 0; j < 4; ++j) {
            const size_t idx = (size_t)(rowb + j) * Ncols + colb;
            ((float*)Cout)[idx] = acc[mf][nf][j] + bs + resid[idx];
          }
        }
      }
    }
  }
}

// ---------------- YaRN RoPE in-place on bf16 qkv (q + k regions) ----------------
__global__ __launch_bounds__(256) void rope_kernel(unsigned short* __restrict__ qkv)
{
  int token = blockIdx.y;
  int p = blockIdx.x * 256 + threadIdx.x;  // 72 heads * 32 pairs = 2304
  if (p >= 72 * 32) return;
  int h = p >> 5, j = p & 31;
  const float log_base = 11.9183905731f;   // ln(150000)
  float fj = (float)j;
  float extrap = expf(-log_base * fj * 0.03125f);   // 1/freq
  float interp = extrap * 0.03125f;                 // 1/(32*freq)
  const float low  = 32.f * logf(4096.f / (32.f * 6.283185307179586f)) / log_base;
  const float high = 32.f * logf(4096.f / 6.283185307179586f) / log_base;
  float ramp = (fj - low) / (high - low);
  float maskv = 1.f - fminf(fmaxf(ramp, 0.f), 1.f);
  float inv_freq = interp * (1.f - maskv) + extrap * maskv;
  float ang = (float)token * inv_freq;
  const float conc = 1.3465735903f;  // 0.1*ln(32)+1
  float s, c;
  sincosf(ang, &s, &c);
  c *= conc; s *= conc;
  size_t base = (size_t)token * QKV_DIM + h * 64 + j;
  float x1 = bf2f(qkv[base]), x2 = bf2f(qkv[base + 32]);
  qkv[base]      = f2bf(x1 * c - x2 * s);
  qkv[base + 32] = f2bf(x2 * c + x1 * s);
}

// ---------------- MFMA sliding-window attention with sinks ----------------
__global__ __launch_bounds__(512) void attn_kernel(
    const unsigned short* __restrict__ qkv, const float* __restrict__ sinks,
    unsigned short* __restrict__ attn)
{
  __shared__ unsigned short Ks[160 * 64];   // [key r][d], 8x16B slots, slot ^= (r&7)
  __shared__ unsigned short Vt[64 * 192];   // [d][key], 24x16B slots, slot ^= (d&7)
  const int tid  = threadIdx.x;
  const int lane = tid & 63;
  const int w    = tid >> 6;
  const int qb = blockIdx.x, kvh = blockIdx.y;
  const int q0 = qb * 32;
  const int kb = q0 - 128;                  // aligned staging base (5 tiles of 32)
  const int h  = lane >> 5;                 // lane half
  const int ql = lane & 31;

  for (int it = w; it < 20; it += 8) {
    int r = it * 8 + (lane >> 3);
    int s = lane & 7;
    int j = kb + r; if (j < 0) j = 0;
    const unsigned short* src =
        qkv + (size_t)j * QKV_DIM + 4096 + kvh * 64 + ((s ^ (r & 7)) * 8);
    gload16(src, &Ks[r * 64 + s * 8]);
  }
  for (int c = tid; c < 2560; c += 512) {
    int jl = c >> 4;                // 0..159
    int d4 = (c & 15) * 4;          // 0..60
    int j = kb + jl; if (j < 0) j = 0;
    ushort4 v4 = *(const ushort4*)&qkv[(size_t)j * QKV_DIM + 4608 + kvh * 64 + d4];
    const unsigned short* pv = (const unsigned short*)&v4;
#pragma unroll
    for (int t = 0; t < 4; ++t) {
      int d = d4 + t;
      int slot = (jl >> 3) ^ (d & 7);
      Vt[d * 192 + slot * 8 + (jl & 7)] = pv[t];
    }
  }
  const int head = kvh * 8 + w;
  const int i_q = q0 + ql;
  short8 qf[4];
  {
    const unsigned short* qp = qkv + (size_t)i_q * QKV_DIM + head * 64 + h * 8;
#pragma unroll
    for (int ks = 0; ks < 4; ++ks) qf[ks] = *(const short8*)(qp + ks * 16);
  }
  __syncthreads();

  const float SC = 0.125f * LOG2E;
  f32x16 oacc0 = (f32x16)(0.f), oacc1 = (f32x16)(0.f);
  float m = -1e30f, l = 0.f;

  const int tstart = qb < 4 ? 4 - qb : 0;
  for (int tt = tstart; tt < 5; ++tt) {
    const int j0 = kb + tt * 32;
    f32x16 sacc = (f32x16)(0.f);
    const int kr = tt * 32 + ql;
#pragma unroll
    for (int ks = 0; ks < 4; ++ks) {
      short8 kf = *(const short8*)&Ks[kr * 64 + (((ks * 2 + h) ^ (kr & 7)) * 8)];
      sacc = __builtin_amdgcn_mfma_f32_32x32x16_bf16(kf, qf[ks], sacc, 0, 0, 0);
    }
    float sc16[16];
    float mt = -INFINITY;
#pragma unroll
    for (int e = 0; e < 16; ++e) {
      int kk = (e & 3) + 8 * (e >> 2) + 4 * h;
      int j = j0 + kk;
      float s2 = sacc[e] * SC;
      bool valid = (j <= i_q) && (j > i_q - 128);
      s2 = valid ? s2 : -INFINITY;
      sc16[e] = s2;
      mt = fmaxf(mt, s2);
    }
    mt = fmaxf(mt, __shfl_xor(mt, 32));
    float mnew = fmaxf(m, mt);
    float r = exp2f(m - mnew);
    l *= r;
    oacc0 *= r;
    oacc1 *= r;
    m = mnew;
    unsigned int wpk[8];
    float ls = 0.f;
#pragma unroll
    for (int e2 = 0; e2 < 8; ++e2) {
      float plo = exp2f(sc16[2 * e2]     - m);
      float phi = exp2f(sc16[2 * e2 + 1] - m);
      ls += plo + phi;
      asm("v_cvt_pk_bf16_f32 %0, %1, %2" : "=v"(wpk[e2]) : "v"(plo), "v"(phi));
    }
    l += ls;
#pragma unroll
    for (int m16 = 0; m16 < 2; ++m16) {
      int go = 2 * m16 + h;
      int gs = 2 * m16 + 1 - h;
      unsigned int x0 = (unsigned int)__shfl_xor((int)wpk[2 * gs],     32);
      unsigned int x1 = (unsigned int)__shfl_xor((int)wpk[2 * gs + 1], 32);
      union { unsigned int u[4]; short8 s; } bu;
      bu.u[0] = h ? x0 : wpk[2 * go];
      bu.u[1] = h ? x1 : wpk[2 * go + 1];
      bu.u[2] = h ? wpk[2 * go]     : x0;
      bu.u[3] = h ? wpk[2 * go + 1] : x1;
      short8 bfrag = bu.s;
#pragma unroll
      for (int dt = 0; dt < 2; ++dt) {
        int d = dt * 32 + ql;
        int slot = (tt * 4 + m16 * 2 + h) ^ (d & 7);
        short8 vf = *(const short8*)&Vt[d * 192 + slot * 8];
        if (dt == 0)
          oacc0 = __builtin_amdgcn_mfma_f32_32x32x16_bf16(vf, bfrag, oacc0, 0, 0, 0);
        else
          oacc1 = __builtin_amdgcn_mfma_f32_32x32x16_bf16(vf, bfrag, oacc1, 0, 0, 0);
      }
    }
  }
  float lt = l + __shfl_xor(l, 32);
  lt += exp2f(sinks[head] * LOG2E - m);
  float inv = 1.f / lt;
  unsigned short* op = attn + (size_t)i_q * 4096 + head * 64;
#pragma unroll
  for (int dt = 0; dt < 2; ++dt) {
#pragma unroll
    for (int g = 0; g < 4; ++g) {
      float f0, f1, f2, f3;
      if (dt == 0) {
        f0 = oacc0[4 * g]; f1 = oacc0[4 * g + 1]; f2 = oacc0[4 * g + 2]; f3 = oacc0[4 * g + 3];
      } else {
        f0 = oacc1[4 * g]; f1 = oacc1[4 * g + 1]; f2 = oacc1[4 * g + 2]; f3 = oacc1[4 * g + 3];
      }
      unsigned int u0, u1;
      asm("v_cvt_pk_bf16_f32 %0, %1, %2" : "=v"(u0) : "v"(f0 * inv), "v"(f1 * inv));
      asm("v_cvt_pk_bf16_f32 %0, %1, %2" : "=v"(u1) : "v"(f2 * inv), "v"(f3 * inv));
      int d = dt * 32 + 8 * g + 4 * h;
      uint2 pr; pr.x = u0; pr.y = u1;
      *(uint2*)(op + d) = pr;
    }
  }
}

extern "C" void kernel_launch(void* const* d_in, const int* in_sizes, int n_in,
                              void* d_out, int out_size, void* d_ws, size_t ws_size,
                              hipStream_t stream)
{
  const float* x      = (const float*)d_in[0];
  const float* nscale = (const float*)d_in[1];
  const float* w_qkv  = (const float*)d_in[2];
  const float* b_qkv  = (const float*)d_in[3];
  const float* sinks  = (const float*)d_in[4];
  const float* w_out  = (const float*)d_in[5];
  const float* b_out  = (const float*)d_in[6];

  char* ws = (char*)d_ws;
  unsigned short* t_bf  = (unsigned short*)(ws);                 // [2048][2880] bf16
  unsigned short* wqkvT = (unsigned short*)(ws + 11796480);      // [5120][2880] bf16
  unsigned short* qkv   = (unsigned short*)(ws + 41287680);      // [2048][5120] bf16
  unsigned short* attn  = (unsigned short*)(ws + 62259200);      // [2048][4096] bf16
  unsigned short* woutT = (unsigned short*)(ws + 79036416);      // [3072 pad][4096] bf16

  rmsnorm_kernel<<<N_TOK, 256, 0, stream>>>(x, nscale, t_bf);
  transpose_cast<<<dim3(5120 / 32, 2880 / 32), 256, 0, stream>>>(w_qkv, wqkvT, 2880, 5120, 2880);
  transpose_cast<<<dim3(2880 / 32, 4096 / 32), 256, 0, stream>>>(w_out, woutT, 4096, 2880, 4096);
  gemm8<1><<<160, 512, 0, stream>>>(t_bf, wqkvT, b_qkv, nullptr, (void*)qkv, 2880, 5120);
  rope_kernel<<<dim3(9, N_TOK), 256, 0, stream>>>(qkv);
  attn_kernel<<<dim3(64, 8), 512, 0, stream>>>(qkv, sinks, attn);
  gemm8<2><<<96, 512, 0, stream>>>(attn, woutT, b_out, x, d_out, 4096, 2880);
}

// Round 4
// 255.883 us; speedup vs baseline: 1.6834x; 1.1724x over previous
//
#include <hip/hip_runtime.h>
#include <hip/hip_bf16.h>
#include <math.h>

#define N_TOK 2048
#define HIDDEN 2880
#define QKV_DIM 5120
#define LOG2E 1.44269504088896340736f

typedef __attribute__((ext_vector_type(8))) short short8;
typedef __attribute__((ext_vector_type(4))) float f32x4;
typedef __attribute__((ext_vector_type(16))) float f32x16;

__device__ __forceinline__ float bf2f(unsigned short u) {
  union { unsigned int i; float f; } c; c.i = ((unsigned int)u) << 16; return c.f;
}
__device__ __forceinline__ unsigned short f2bf(float f) {
  union { float f; unsigned int i; } c; c.f = f;
  unsigned int i = c.i;
  return (unsigned short)((i + 0x7FFFu + ((i >> 16) & 1u)) >> 16);
}
__device__ __forceinline__ void gload16(const void* g, void* l) {
  __builtin_amdgcn_global_load_lds((const __attribute__((address_space(1))) void*)g,
                                   (__attribute__((address_space(3))) void*)l, 16, 0, 0);
}

// ---------------- RMSNorm (fp32 in -> bf16 out) ----------------
__global__ __launch_bounds__(256) void rmsnorm_kernel(
    const float* __restrict__ x, const float* __restrict__ scale,
    unsigned short* __restrict__ t)
{
  int row = blockIdx.x;
  const float* xr = x + (size_t)row * HIDDEN;
  float ss = 0.f;
  for (int i = threadIdx.x; i < HIDDEN / 4; i += 256) {
    float4 v = ((const float4*)xr)[i];
    ss += v.x * v.x + v.y * v.y + v.z * v.z + v.w * v.w;
  }
#pragma unroll
  for (int off = 32; off; off >>= 1) ss += __shfl_down(ss, off, 64);
  __shared__ float red[4];
  if ((threadIdx.x & 63) == 0) red[threadIdx.x >> 6] = ss;
  __syncthreads();
  float total = red[0] + red[1] + red[2] + red[3];
  float rinv = rsqrtf(total / (float)HIDDEN + 1e-5f);
  for (int i = threadIdx.x; i < HIDDEN / 4; i += 256) {
    float4 v = ((const float4*)xr)[i];
    float4 s4 = ((const float4*)scale)[i];
    union { unsigned short u[4]; uint2 p; } pk;
    pk.u[0] = f2bf(v.x * rinv * s4.x);
    pk.u[1] = f2bf(v.y * rinv * s4.y);
    pk.u[2] = f2bf(v.z * rinv * s4.z);
    pk.u[3] = f2bf(v.w * rinv * s4.w);
    *(uint2*)&t[(size_t)row * HIDDEN + i * 4] = pk.p;
  }
}

// ---------------- transpose + cast fp32[R][C] -> bf16[C][R] ----------------
__global__ __launch_bounds__(256) void transpose_cast(
    const float* __restrict__ in, unsigned short* __restrict__ out,
    int R, int C, int outStride)
{
  __shared__ float tile[32][33];
  int c0 = blockIdx.x * 32, r0 = blockIdx.y * 32;
  int tx = threadIdx.x & 31, ty = threadIdx.x >> 5;
#pragma unroll
  for (int rr = ty; rr < 32; rr += 8)
    tile[rr][tx] = in[(size_t)(r0 + rr) * C + c0 + tx];
  __syncthreads();
#pragma unroll
  for (int rr = ty; rr < 32; rr += 8)
    out[(size_t)(c0 + rr) * outStride + r0 + tx] = f2bf(tile[tx][rr]);
}

// ---------------- 256x256 free-run GEMM: C = A[M,K] * Bt[N,K]^T ----------------
// 512 threads = 8 waves (2M x 4N), BK=64, 128 KiB LDS double-buffer.
// Per K-tile: [vmcnt(0) on own loads issued a full tile ago] [1 barrier]
// [issue 8 prefetch chunks] [24 ds_read_b128 + 64 MFMA, compiler-scheduled].
// No intra-tile barriers: reads hit buf(t), stages write buf(t+1).
// LDS: 16B unit u swizzled u_phys = u_log ^ ((row>>1)&3) -> 2-way (free).
template <int EPI>
__global__ __launch_bounds__(512, 2) void gemm8(
    const unsigned short* __restrict__ A,
    const unsigned short* __restrict__ Bt,
    const float* __restrict__ bias,
    const float* __restrict__ resid,
    void* __restrict__ Cout,
    int K, int Ncols)
{
  __shared__ char smem_[131072];
  const int tid = threadIdx.x;
  const int lane = tid & 63;
  const int w = tid >> 6;
  const int fr = lane & 15, fq = lane >> 4;
  const int wr = w >> 2, wc = w & 3;

  // bijective XCD swizzle (nwg % 8 == 0)
  const int nwg = gridDim.x;
  const int cpx = nwg >> 3;
  const int wg = (blockIdx.x & 7) * cpx + (blockIdx.x >> 3);
  const int by = wg & 7, bx = wg >> 3;
  const int row0 = by * 256, col0 = bx * 256;

  // ---- staging addresses (8 chunks/K-tile; c: 0,1=Bkk0 2,3=Akk0 4,5=Bkk1 6,7=Akk1)
  const unsigned short* gsrc[8];
  int ldsoff[8];
  {
    const int rloc = w * 16 + (lane >> 2);            // + (c&1)*128
    const int u2s = (lane & 3) ^ ((lane >> 3) & 3);   // logical unit for this lane's slot
#pragma unroll
    for (int c = 0; c < 8; ++c) {
      const int isA = (c == 2 || c == 3 || c == 6 || c == 7);
      const int kb = c >> 2;
      const int r = (c & 1) * 128 + rloc;
      const int gc = kb * 32 + u2s * 8;
      gsrc[c] = isA ? (A + (size_t)(row0 + r) * K + gc)
                    : (Bt + (size_t)(col0 + r) * K + gc);
      ldsoff[c] = (isA ? 0 : 32768) + kb * 16384 + (c & 1) * 8192 + w * 1024 + lane * 16;
    }
  }
  // ---- ds_read offsets (phys u = fq ^ ((row>>1)&3); row = ..16k.. + fr)
  const int urd = (fq ^ ((fr >> 1) & 3)) * 16;
  const int aoff = (wr * 128 + fr) * 64 + urd;
  const int boff = 32768 + (wc * 64 + fr) * 64 + urd;

  f32x4 acc[8][4];
#pragma unroll
  for (int mf = 0; mf < 8; ++mf)
#pragma unroll
    for (int nf = 0; nf < 4; ++nf) acc[mf][nf] = (f32x4)0.f;

  const int NT = K >> 6;

#define ISSUE(c) gload16(gsrc[c] + ktn, smem_ + nbufo + ldsoff[c])
#define RD_A(mf, kk) (*(const short8*)(smem_ + bufo + (kk)*16384 + (mf)*1024 + aoff))
#define RD_B(nf, kk) (*(const short8*)(smem_ + bufo + (kk)*16384 + (nf)*1024 + boff))
#define MM(mf, ar) \
  acc[mf][0] = __builtin_amdgcn_mfma_f32_16x16x32_bf16(ar, b0, acc[mf][0], 0, 0, 0); \
  acc[mf][1] = __builtin_amdgcn_mfma_f32_16x16x32_bf16(ar, b1, acc[mf][1], 0, 0, 0); \
  acc[mf][2] = __builtin_amdgcn_mfma_f32_16x16x32_bf16(ar, b2, acc[mf][2], 0, 0, 0); \
  acc[mf][3] = __builtin_amdgcn_mfma_f32_16x16x32_bf16(ar, b3, acc[mf][3], 0, 0, 0);

  // prologue: stage tile 0 into buffer 0
  {
    const int ktn = 0, nbufo = 0;
#pragma unroll
    for (int c = 0; c < 8; ++c) gload16(gsrc[c] + ktn, smem_ + nbufo + ldsoff[c]);
  }

  for (int t = 0; t < NT; ++t) {
    const int bufo = (t & 1) * 65536;
    const int nbufo = bufo ^ 65536;
    const int ktn = (t + 1) * 64;
    const bool pref = (t + 1) < NT;

    // Wait for OWN chunks of tile t (issued a full tile-body ago). Nothing
    // newer is outstanding at this point in program order -> not a drain.
    asm volatile("s_waitcnt vmcnt(0)" ::: "memory");
    // All waves landed their pieces of tile t; also fences buf(t+1)=buf(t-1)
    // reads (tile t-1 body) from the stages below.
    __builtin_amdgcn_s_barrier();

    if (pref) { ISSUE(0); ISSUE(1); ISSUE(2); ISSUE(3); }

    short8 a0, a1, a2, a3, a4, a5, a6, a7, b0, b1, b2, b3;
    // ---- kk0 half ----
    b0 = RD_B(0, 0); b1 = RD_B(1, 0); b2 = RD_B(2, 0); b3 = RD_B(3, 0);
    a0 = RD_A(0, 0); a1 = RD_A(1, 0); a2 = RD_A(2, 0); a3 = RD_A(3, 0);
    a4 = RD_A(4, 0); a5 = RD_A(5, 0); a6 = RD_A(6, 0); a7 = RD_A(7, 0);
    __builtin_amdgcn_s_setprio(1);
    MM(0, a0) MM(1, a1) MM(2, a2) MM(3, a3)
    MM(4, a4) MM(5, a5) MM(6, a6) MM(7, a7)
    __builtin_amdgcn_s_setprio(0);

    if (pref) { ISSUE(4); ISSUE(5); ISSUE(6); ISSUE(7); }

    // ---- kk1 half ----
    b0 = RD_B(0, 1); b1 = RD_B(1, 1); b2 = RD_B(2, 1); b3 = RD_B(3, 1);
    a0 = RD_A(0, 1); a1 = RD_A(1, 1); a2 = RD_A(2, 1); a3 = RD_A(3, 1);
    a4 = RD_A(4, 1); a5 = RD_A(5, 1); a6 = RD_A(6, 1); a7 = RD_A(7, 1);
    __builtin_amdgcn_s_setprio(1);
    MM(0, a0) MM(1, a1) MM(2, a2) MM(3, a3)
    MM(4, a4) MM(5, a5) MM(6, a6) MM(7, a7)
    __builtin_amdgcn_s_setprio(0);
  }
#undef ISSUE
#undef RD_A
#undef RD_B
#undef MM

  // ---- epilogue ----
#pragma unroll
  for (int mf = 0; mf < 8; ++mf) {
#pragma unroll
    for (int nf = 0; nf < 4; ++nf) {
      const int colb = col0 + wc * 64 + nf * 16 + fr;
      const int rowb = row0 + wr * 128 + mf * 16 + fq * 4;
      if (EPI == 1) {
        const float bs = bias[colb];
#pragma unroll
        for (int j = 0; j < 4; ++j)
          ((unsigned short*)Cout)[(size_t)(rowb + j) * Ncols + colb] =
              f2bf(acc[mf][nf][j] + bs);
      } else {
        if (colb < Ncols) {
          const float bs = bias[colb];
#pragma unroll
          for (int j = 0; j < 4; ++j) {
            const size_t idx = (size_t)(rowb + j) * Ncols + colb;
            ((float*)Cout)[idx] = acc[mf][nf][j] + bs + resid[idx];
          }
        }
      }
    }
  }
}

// ---------------- YaRN RoPE in-place on bf16 qkv (q + k regions) ----------------
__global__ __launch_bounds__(256) void rope_kernel(unsigned short* __restrict__ qkv)
{
  int token = blockIdx.y;
  int p = blockIdx.x * 256 + threadIdx.x;  // 72 heads * 32 pairs = 2304
  if (p >= 72 * 32) return;
  int h = p >> 5, j = p & 31;
  const float log_base = 11.9183905731f;   // ln(150000)
  float fj = (float)j;
  float extrap = expf(-log_base * fj * 0.03125f);   // 1/freq
  float interp = extrap * 0.03125f;                 // 1/(32*freq)
  const float low  = 32.f * logf(4096.f / (32.f * 6.283185307179586f)) / log_base;
  const float high = 32.f * logf(4096.f / 6.283185307179586f) / log_base;
  float ramp = (fj - low) / (high - low);
  float maskv = 1.f - fminf(fmaxf(ramp, 0.f), 1.f);
  float inv_freq = interp * (1.f - maskv) + extrap * maskv;
  float ang = (float)token * inv_freq;
  const float conc = 1.3465735903f;  // 0.1*ln(32)+1
  float s, c;
  sincosf(ang, &s, &c);
  c *= conc; s *= conc;
  size_t base = (size_t)token * QKV_DIM + h * 64 + j;
  float x1 = bf2f(qkv[base]), x2 = bf2f(qkv[base + 32]);
  qkv[base]      = f2bf(x1 * c - x2 * s);
  qkv[base + 32] = f2bf(x2 * c + x1 * s);
}

// ---------------- MFMA sliding-window attention with sinks ----------------
__global__ __launch_bounds__(512) void attn_kernel(
    const unsigned short* __restrict__ qkv, const float* __restrict__ sinks,
    unsigned short* __restrict__ attn)
{
  __shared__ unsigned short Ks[160 * 64];   // [key r][d], 8x16B slots, slot ^= (r&7)
  __shared__ unsigned short Vt[64 * 192];   // [d][key], 24x16B slots, slot ^= (d&7)
  const int tid  = threadIdx.x;
  const int lane = tid & 63;
  const int w    = tid >> 6;
  const int qb = blockIdx.x, kvh = blockIdx.y;
  const int q0 = qb * 32;
  const int kb = q0 - 128;                  // aligned staging base (5 tiles of 32)
  const int h  = lane >> 5;                 // lane half
  const int ql = lane & 31;

  for (int it = w; it < 20; it += 8) {
    int r = it * 8 + (lane >> 3);
    int s = lane & 7;
    int j = kb + r; if (j < 0) j = 0;
    const unsigned short* src =
        qkv + (size_t)j * QKV_DIM + 4096 + kvh * 64 + ((s ^ (r & 7)) * 8);
    gload16(src, &Ks[r * 64 + s * 8]);
  }
  for (int c = tid; c < 2560; c += 512) {
    int jl = c >> 4;                // 0..159
    int d4 = (c & 15) * 4;          // 0..60
    int j = kb + jl; if (j < 0) j = 0;
    ushort4 v4 = *(const ushort4*)&qkv[(size_t)j * QKV_DIM + 4608 + kvh * 64 + d4];
    const unsigned short* pv = (const unsigned short*)&v4;
#pragma unroll
    for (int t = 0; t < 4; ++t) {
      int d = d4 + t;
      int slot = (jl >> 3) ^ (d & 7);
      Vt[d * 192 + slot * 8 + (jl & 7)] = pv[t];
    }
  }
  const int head = kvh * 8 + w;
  const int i_q = q0 + ql;
  short8 qf[4];
  {
    const unsigned short* qp = qkv + (size_t)i_q * QKV_DIM + head * 64 + h * 8;
#pragma unroll
    for (int ks = 0; ks < 4; ++ks) qf[ks] = *(const short8*)(qp + ks * 16);
  }
  __syncthreads();

  const float SC = 0.125f * LOG2E;
  f32x16 oacc0 = (f32x16)(0.f), oacc1 = (f32x16)(0.f);
  float m = -1e30f, l = 0.f;

  const int tstart = qb < 4 ? 4 - qb : 0;
  for (int tt = tstart; tt < 5; ++tt) {
    const int j0 = kb + tt * 32;
    f32x16 sacc = (f32x16)(0.f);
    const int kr = tt * 32 + ql;
#pragma unroll
    for (int ks = 0; ks < 4; ++ks) {
      short8 kf = *(const short8*)&Ks[kr * 64 + (((ks * 2 + h) ^ (kr & 7)) * 8)];
      sacc = __builtin_amdgcn_mfma_f32_32x32x16_bf16(kf, qf[ks], sacc, 0, 0, 0);
    }
    float sc16[16];
    float mt = -INFINITY;
#pragma unroll
    for (int e = 0; e < 16; ++e) {
      int kk = (e & 3) + 8 * (e >> 2) + 4 * h;
      int j = j0 + kk;
      float s2 = sacc[e] * SC;
      bool valid = (j <= i_q) && (j > i_q - 128);
      s2 = valid ? s2 : -INFINITY;
      sc16[e] = s2;
      mt = fmaxf(mt, s2);
    }
    mt = fmaxf(mt, __shfl_xor(mt, 32));
    float mnew = fmaxf(m, mt);
    float r = exp2f(m - mnew);
    l *= r;
    oacc0 *= r;
    oacc1 *= r;
    m = mnew;
    unsigned int wpk[8];
    float ls = 0.f;
#pragma unroll
    for (int e2 = 0; e2 < 8; ++e2) {
      float plo = exp2f(sc16[2 * e2]     - m);
      float phi = exp2f(sc16[2 * e2 + 1] - m);
      ls += plo + phi;
      asm("v_cvt_pk_bf16_f32 %0, %1, %2" : "=v"(wpk[e2]) : "v"(plo), "v"(phi));
    }
    l += ls;
#pragma unroll
    for (int m16 = 0; m16 < 2; ++m16) {
      int go = 2 * m16 + h;
      int gs = 2 * m16 + 1 - h;
      unsigned int x0 = (unsigned int)__shfl_xor((int)wpk[2 * gs],     32);
      unsigned int x1 = (unsigned int)__shfl_xor((int)wpk[2 * gs + 1], 32);
      union { unsigned int u[4]; short8 s; } bu;
      bu.u[0] = h ? x0 : wpk[2 * go];
      bu.u[1] = h ? x1 : wpk[2 * go + 1];
      bu.u[2] = h ? wpk[2 * go]     : x0;
      bu.u[3] = h ? wpk[2 * go + 1] : x1;
      short8 bfrag = bu.s;
#pragma unroll
      for (int dt = 0; dt < 2; ++dt) {
        int d = dt * 32 + ql;
        int slot = (tt * 4 + m16 * 2 + h) ^ (d & 7);
        short8 vf = *(const short8*)&Vt[d * 192 + slot * 8];
        if (dt == 0)
          oacc0 = __builtin_amdgcn_mfma_f32_32x32x16_bf16(vf, bfrag, oacc0, 0, 0, 0);
        else
          oacc1 = __builtin_amdgcn_mfma_f32_32x32x16_bf16(vf, bfrag, oacc1, 0, 0, 0);
      }
    }
  }
  float lt = l + __shfl_xor(l, 32);
  lt += exp2f(sinks[head] * LOG2E - m);
  float inv = 1.f / lt;
  unsigned short* op = attn + (size_t)i_q * 4096 + head * 64;
#pragma unroll
  for (int dt = 0; dt < 2; ++dt) {
#pragma unroll
    for (int g = 0; g < 4; ++g) {
      float f0, f1, f2, f3;
      if (dt == 0) {
        f0 = oacc0[4 * g]; f1 = oacc0[4 * g + 1]; f2 = oacc0[4 * g + 2]; f3 = oacc0[4 * g + 3];
      } else {
        f0 = oacc1[4 * g]; f1 = oacc1[4 * g + 1]; f2 = oacc1[4 * g + 2]; f3 = oacc1[4 * g + 3];
      }
      unsigned int u0, u1;
      asm("v_cvt_pk_bf16_f32 %0, %1, %2" : "=v"(u0) : "v"(f0 * inv), "v"(f1 * inv));
      asm("v_cvt_pk_bf16_f32 %0, %1, %2" : "=v"(u1) : "v"(f2 * inv), "v"(f3 * inv));
      int d = dt * 32 + 8 * g + 4 * h;
      uint2 pr; pr.x = u0; pr.y = u1;
      *(uint2*)(op + d) = pr;
    }
  }
}

extern "C" void kernel_launch(void* const* d_in, const int* in_sizes, int n_in,
                              void* d_out, int out_size, void* d_ws, size_t ws_size,
                              hipStream_t stream)
{
  const float* x      = (const float*)d_in[0];
  const float* nscale = (const float*)d_in[1];
  const float* w_qkv  = (const float*)d_in[2];
  const float* b_qkv  = (const float*)d_in[3];
  const float* sinks  = (const float*)d_in[4];
  const float* w_out  = (const float*)d_in[5];
  const float* b_out  = (const float*)d_in[6];

  char* ws = (char*)d_ws;
  unsigned short* t_bf  = (unsigned short*)(ws);                 // [2048][2880] bf16
  unsigned short* wqkvT = (unsigned short*)(ws + 11796480);      // [5120][2880] bf16
  unsigned short* qkv   = (unsigned short*)(ws + 41287680);      // [2048][5120] bf16
  unsigned short* attn  = (unsigned short*)(ws + 62259200);      // [2048][4096] bf16
  unsigned short* woutT = (unsigned short*)(ws + 79036416);      // [3072 pad][4096] bf16

  rmsnorm_kernel<<<N_TOK, 256, 0, stream>>>(x, nscale, t_bf);
  transpose_cast<<<dim3(5120 / 32, 2880 / 32), 256, 0, stream>>>(w_qkv, wqkvT, 2880, 5120, 2880);
  transpose_cast<<<dim3(2880 / 32, 4096 / 32), 256, 0, stream>>>(w_out, woutT, 4096, 2880, 4096);
  gemm8<1><<<160, 512, 0, stream>>>(t_bf, wqkvT, b_qkv, nullptr, (void*)qkv, 2880, 5120);
  rope_kernel<<<dim3(9, N_TOK), 256, 0, stream>>>(qkv);
  attn_kernel<<<dim3(64, 8), 512, 0, stream>>>(qkv, sinks, attn);
  gemm8<2><<<96, 512, 0, stream>>>(attn, woutT, b_out, x, d_out, 4096, 2880);
}

// Round 5
// 203.384 us; speedup vs baseline: 2.1179x; 1.2581x over previous
//
#include <hip/hip_runtime.h>
#include <hip/hip_bf16.h>
#include <math.h>

#define N_TOK 2048
#define HIDDEN 2880
#define QKV_DIM 5120
#define LOG2E 1.44269504088896340736f

typedef __attribute__((ext_vector_type(8))) short short8;
typedef __attribute__((ext_vector_type(4))) float f32x4;
typedef __attribute__((ext_vector_type(16))) float f32x16;

__device__ __forceinline__ float bf2f(unsigned short u) {
  union { unsigned int i; float f; } c; c.i = ((unsigned int)u) << 16; return c.f;
}
__device__ __forceinline__ unsigned short f2bf(float f) {
  union { float f; unsigned int i; } c; c.f = f;
  unsigned int i = c.i;
  return (unsigned short)((i + 0x7FFFu + ((i >> 16) & 1u)) >> 16);
}
__device__ __forceinline__ void gload16(const void* g, void* l) {
  __builtin_amdgcn_global_load_lds((const __attribute__((address_space(1))) void*)g,
                                   (__attribute__((address_space(3))) void*)l, 16, 0, 0);
}

// ---------------- RMSNorm (fp32 in -> bf16 out) ----------------
__global__ __launch_bounds__(256) void rmsnorm_kernel(
    const float* __restrict__ x, const float* __restrict__ scale,
    unsigned short* __restrict__ t)
{
  int row = blockIdx.x;
  const float* xr = x + (size_t)row * HIDDEN;
  float ss = 0.f;
  for (int i = threadIdx.x; i < HIDDEN / 4; i += 256) {
    float4 v = ((const float4*)xr)[i];
    ss += v.x * v.x + v.y * v.y + v.z * v.z + v.w * v.w;
  }
#pragma unroll
  for (int off = 32; off; off >>= 1) ss += __shfl_down(ss, off, 64);
  __shared__ float red[4];
  if ((threadIdx.x & 63) == 0) red[threadIdx.x >> 6] = ss;
  __syncthreads();
  float total = red[0] + red[1] + red[2] + red[3];
  float rinv = rsqrtf(total / (float)HIDDEN + 1e-5f);
  for (int i = threadIdx.x; i < HIDDEN / 4; i += 256) {
    float4 v = ((const float4*)xr)[i];
    float4 s4 = ((const float4*)scale)[i];
    union { unsigned short u[4]; uint2 p; } pk;
    pk.u[0] = f2bf(v.x * rinv * s4.x);
    pk.u[1] = f2bf(v.y * rinv * s4.y);
    pk.u[2] = f2bf(v.z * rinv * s4.z);
    pk.u[3] = f2bf(v.w * rinv * s4.w);
    *(uint2*)&t[(size_t)row * HIDDEN + i * 4] = pk.p;
  }
}

// ---------------- transpose + cast fp32[R][C] -> bf16[C][R] ----------------
__global__ __launch_bounds__(256) void transpose_cast(
    const float* __restrict__ in, unsigned short* __restrict__ out,
    int R, int C, int outStride)
{
  __shared__ float tile[32][33];
  int c0 = blockIdx.x * 32, r0 = blockIdx.y * 32;
  int tx = threadIdx.x & 31, ty = threadIdx.x >> 5;
#pragma unroll
  for (int rr = ty; rr < 32; rr += 8)
    tile[rr][tx] = in[(size_t)(r0 + rr) * C + c0 + tx];
  __syncthreads();
#pragma unroll
  for (int rr = ty; rr < 32; rr += 8)
    out[(size_t)(c0 + rr) * outStride + r0 + tx] = f2bf(tile[tx][rr]);
}

// ---------------- 128 x (NF*64) free-run GEMM: C = A[M,K] * Bt[N,K]^T ----------------
// 512 threads = 8 waves (2M x 4N): wave rows = 64 (4 frags), cols = NF*16.
// BK=64, double-buffered LDS. Per K-tile: [vmcnt(0)] [1 barrier]
// [issue prefetch chunks] [ds_read + MFMA, compiler-scheduled].
// LDS layout per operand: [kk(2)][rows][4 x 16B units], unit swizzled
// u_phys = u_log ^ ((row>>1)&3) -> 2-way bank aliasing (free).
// Staged via global_load_lds: per wave LDS dest = base + lane*16 (linear).
// QKV: NF=5 (BN=320, grid 16x16=256). Out: NF=3 (BN=192, grid 16x15=240).
template <int NF, int EPI>
__global__ __launch_bounds__(512, 2) void gemm8(
    const unsigned short* __restrict__ A,
    const unsigned short* __restrict__ Bt,
    const float* __restrict__ bias,
    const float* __restrict__ resid,
    void* __restrict__ Cout,
    int K, int Ncols)
{
  constexpr int BUFSZ = 16384 + NF * 8192;   // A: 16KB, B: BN*128B
  constexpr int NCH = 2 + NF;                // 16B-chunks per thread per K-tile
  constexpr int HALF = NCH / 2;
  __shared__ char smem_[2 * BUFSZ];
  const int tid = threadIdx.x;
  const int lane = tid & 63;
  const int w = tid >> 6;
  const int fr = lane & 15, fq = lane >> 4;
  const int wr = w >> 2, wc = w & 3;

  // bijective XCD swizzle (nwg % 8 == 0)
  const int nwg = gridDim.x;
  const int cpx = nwg >> 3;
  const int wg = (blockIdx.x & 7) * cpx + (blockIdx.x >> 3);
  const int by = wg & 15, bx = wg >> 4;      // M/128 == 16 for both GEMMs
  const int row0 = by * 128, col0 = bx * (NF * 64);

  // ---- staging addresses: flat unit index g = tid + 512*c
  // A units: 2kk x 128rows x 4u = 1024; B units: 2kk x BN x 4u = NF*512
  const unsigned short* gsrc[NCH];
  int ldsoff[NCH];
#pragma unroll
  for (int c = 0; c < NCH; ++c) {
    int g = tid + 512 * c;
    if (g < 1024) {
      int kk = g >> 9, rr = (g >> 2) & 127, u = g & 3;
      gsrc[c] = A + (size_t)(row0 + rr) * K + kk * 32 + ((u ^ ((rr >> 1) & 3)) * 8);
      ldsoff[c] = kk * 8192 + rr * 64 + u * 16;
    } else {
      int g2 = g - 1024;
      int kk = g2 / (NF * 256);
      int rm = g2 - kk * (NF * 256);
      int rr = rm >> 2, u = rm & 3;
      gsrc[c] = Bt + (size_t)(col0 + rr) * K + kk * 32 + ((u ^ ((rr >> 1) & 3)) * 8);
      ldsoff[c] = 16384 + kk * (NF * 4096) + rr * 64 + u * 16;
    }
  }
  // ---- ds_read offsets (phys u = fq ^ ((row>>1)&3); row base mult of 16)
  const int urd = (fq ^ ((fr >> 1) & 3)) * 16;
  const int aoffb = (wr * 64 + fr) * 64 + urd;                 // + mf*1024 + kk*8192
  const int boffb = 16384 + (wc * NF * 16 + fr) * 64 + urd;    // + nf*1024 + kk*NF*4096

  f32x4 acc[4][NF];
#pragma unroll
  for (int mf = 0; mf < 4; ++mf)
#pragma unroll
    for (int nf = 0; nf < NF; ++nf) acc[mf][nf] = (f32x4)0.f;

  const int NT = K >> 6;

#define ISSUE(c) gload16(gsrc[c] + ktn, smem_ + nbufo + ldsoff[c])
#define RD_A(mf, kk) (*(const short8*)(smem_ + bufo + (kk)*8192 + (mf)*1024 + aoffb))
#define RD_B(nf, kk) (*(const short8*)(smem_ + bufo + (kk)*(NF*4096) + (nf)*1024 + boffb))

  // prologue: stage tile 0 into buffer 0
  {
    const int ktn = 0, nbufo = 0;
#pragma unroll
    for (int c = 0; c < NCH; ++c) gload16(gsrc[c] + ktn, smem_ + nbufo + ldsoff[c]);
  }

  for (int t = 0; t < NT; ++t) {
    const int bufo = (t & 1) * BUFSZ;
    const int nbufo = bufo ^ BUFSZ;
    const int ktn = (t + 1) * 64;
    const bool pref = (t + 1) < NT;

    // Wait for OWN chunks of tile t (issued a full tile-body ago).
    asm volatile("s_waitcnt vmcnt(0)" ::: "memory");
    __builtin_amdgcn_s_barrier();

    if (pref) {
#pragma unroll
      for (int c = 0; c < HALF; ++c) ISSUE(c);
    }

    short8 afr[4], bfr[NF];
    // ---- kk0 half ----
#pragma unroll
    for (int nf = 0; nf < NF; ++nf) bfr[nf] = RD_B(nf, 0);
#pragma unroll
    for (int mf = 0; mf < 4; ++mf) afr[mf] = RD_A(mf, 0);
    __builtin_amdgcn_s_setprio(1);
#pragma unroll
    for (int mf = 0; mf < 4; ++mf)
#pragma unroll
      for (int nf = 0; nf < NF; ++nf)
        acc[mf][nf] = __builtin_amdgcn_mfma_f32_16x16x32_bf16(afr[mf], bfr[nf], acc[mf][nf], 0, 0, 0);
    __builtin_amdgcn_s_setprio(0);

    if (pref) {
#pragma unroll
      for (int c = HALF; c < NCH; ++c) ISSUE(c);
    }

    // ---- kk1 half ----
#pragma unroll
    for (int nf = 0; nf < NF; ++nf) bfr[nf] = RD_B(nf, 1);
#pragma unroll
    for (int mf = 0; mf < 4; ++mf) afr[mf] = RD_A(mf, 1);
    __builtin_amdgcn_s_setprio(1);
#pragma unroll
    for (int mf = 0; mf < 4; ++mf)
#pragma unroll
      for (int nf = 0; nf < NF; ++nf)
        acc[mf][nf] = __builtin_amdgcn_mfma_f32_16x16x32_bf16(afr[mf], bfr[nf], acc[mf][nf], 0, 0, 0);
    __builtin_amdgcn_s_setprio(0);
  }
#undef ISSUE
#undef RD_A
#undef RD_B

  // ---- epilogue (grids exact in N for both shapes; no col guard) ----
#pragma unroll
  for (int mf = 0; mf < 4; ++mf) {
#pragma unroll
    for (int nf = 0; nf < NF; ++nf) {
      const int colb = col0 + wc * NF * 16 + nf * 16 + fr;
      const int rowb = row0 + wr * 64 + mf * 16 + fq * 4;
      const float bs = bias[colb];
      if (EPI == 1) {
#pragma unroll
        for (int j = 0; j < 4; ++j)
          ((unsigned short*)Cout)[(size_t)(rowb + j) * Ncols + colb] =
              f2bf(acc[mf][nf][j] + bs);
      } else {
#pragma unroll
        for (int j = 0; j < 4; ++j) {
          const size_t idx = (size_t)(rowb + j) * Ncols + colb;
          ((float*)Cout)[idx] = acc[mf][nf][j] + bs + resid[idx];
        }
      }
    }
  }
}

// ---------------- YaRN RoPE in-place on bf16 qkv (q + k regions) ----------------
__global__ __launch_bounds__(256) void rope_kernel(unsigned short* __restrict__ qkv)
{
  int token = blockIdx.y;
  int p = blockIdx.x * 256 + threadIdx.x;  // 72 heads * 32 pairs = 2304
  if (p >= 72 * 32) return;
  int h = p >> 5, j = p & 31;
  const float log_base = 11.9183905731f;   // ln(150000)
  float fj = (float)j;
  float extrap = expf(-log_base * fj * 0.03125f);   // 1/freq
  float interp = extrap * 0.03125f;                 // 1/(32*freq)
  const float low  = 32.f * logf(4096.f / (32.f * 6.283185307179586f)) / log_base;
  const float high = 32.f * logf(4096.f / 6.283185307179586f) / log_base;
  float ramp = (fj - low) / (high - low);
  float maskv = 1.f - fminf(fmaxf(ramp, 0.f), 1.f);
  float inv_freq = interp * (1.f - maskv) + extrap * maskv;
  float ang = (float)token * inv_freq;
  const float conc = 1.3465735903f;  // 0.1*ln(32)+1
  float s, c;
  sincosf(ang, &s, &c);
  c *= conc; s *= conc;
  size_t base = (size_t)token * QKV_DIM + h * 64 + j;
  float x1 = bf2f(qkv[base]), x2 = bf2f(qkv[base + 32]);
  qkv[base]      = f2bf(x1 * c - x2 * s);
  qkv[base + 32] = f2bf(x2 * c + x1 * s);
}

// ---------------- MFMA sliding-window attention with sinks ----------------
__global__ __launch_bounds__(512) void attn_kernel(
    const unsigned short* __restrict__ qkv, const float* __restrict__ sinks,
    unsigned short* __restrict__ attn)
{
  __shared__ unsigned short Ks[160 * 64];   // [key r][d], 8x16B slots, slot ^= (r&7)
  __shared__ unsigned short Vt[64 * 192];   // [d][key], 24x16B slots, slot ^= (d&7)
  const int tid  = threadIdx.x;
  const int lane = tid & 63;
  const int w    = tid >> 6;
  const int qb = blockIdx.x, kvh = blockIdx.y;
  const int q0 = qb * 32;
  const int kb = q0 - 128;                  // aligned staging base (5 tiles of 32)
  const int h  = lane >> 5;                 // lane half
  const int ql = lane & 31;

  for (int it = w; it < 20; it += 8) {
    int r = it * 8 + (lane >> 3);
    int s = lane & 7;
    int j = kb + r; if (j < 0) j = 0;
    const unsigned short* src =
        qkv + (size_t)j * QKV_DIM + 4096 + kvh * 64 + ((s ^ (r & 7)) * 8);
    gload16(src, &Ks[r * 64 + s * 8]);
  }
  for (int c = tid; c < 2560; c += 512) {
    int jl = c >> 4;                // 0..159
    int d4 = (c & 15) * 4;          // 0..60
    int j = kb + jl; if (j < 0) j = 0;
    ushort4 v4 = *(const ushort4*)&qkv[(size_t)j * QKV_DIM + 4608 + kvh * 64 + d4];
    const unsigned short* pv = (const unsigned short*)&v4;
#pragma unroll
    for (int t = 0; t < 4; ++t) {
      int d = d4 + t;
      int slot = (jl >> 3) ^ (d & 7);
      Vt[d * 192 + slot * 8 + (jl & 7)] = pv[t];
    }
  }
  const int head = kvh * 8 + w;
  const int i_q = q0 + ql;
  short8 qf[4];
  {
    const unsigned short* qp = qkv + (size_t)i_q * QKV_DIM + head * 64 + h * 8;
#pragma unroll
    for (int ks = 0; ks < 4; ++ks) qf[ks] = *(const short8*)(qp + ks * 16);
  }
  __syncthreads();

  const float SC = 0.125f * LOG2E;
  f32x16 oacc0 = (f32x16)(0.f), oacc1 = (f32x16)(0.f);
  float m = -1e30f, l = 0.f;

  const int tstart = qb < 4 ? 4 - qb : 0;
  for (int tt = tstart; tt < 5; ++tt) {
    const int j0 = kb + tt * 32;
    f32x16 sacc = (f32x16)(0.f);
    const int kr = tt * 32 + ql;
#pragma unroll
    for (int ks = 0; ks < 4; ++ks) {
      short8 kf = *(const short8*)&Ks[kr * 64 + (((ks * 2 + h) ^ (kr & 7)) * 8)];
      sacc = __builtin_amdgcn_mfma_f32_32x32x16_bf16(kf, qf[ks], sacc, 0, 0, 0);
    }
    float sc16[16];
    float mt = -INFINITY;
#pragma unroll
    for (int e = 0; e < 16; ++e) {
      int kk = (e & 3) + 8 * (e >> 2) + 4 * h;
      int j = j0 + kk;
      float s2 = sacc[e] * SC;
      bool valid = (j <= i_q) && (j > i_q - 128);
      s2 = valid ? s2 : -INFINITY;
      sc16[e] = s2;
      mt = fmaxf(mt, s2);
    }
    mt = fmaxf(mt, __shfl_xor(mt, 32));
    float mnew = fmaxf(m, mt);
    float r = exp2f(m - mnew);
    l *= r;
    oacc0 *= r;
    oacc1 *= r;
    m = mnew;
    unsigned int wpk[8];
    float ls = 0.f;
#pragma unroll
    for (int e2 = 0; e2 < 8; ++e2) {
      float plo = exp2f(sc16[2 * e2]     - m);
      float phi = exp2f(sc16[2 * e2 + 1] - m);
      ls += plo + phi;
      asm("v_cvt_pk_bf16_f32 %0, %1, %2" : "=v"(wpk[e2]) : "v"(plo), "v"(phi));
    }
    l += ls;
#pragma unroll
    for (int m16 = 0; m16 < 2; ++m16) {
      int go = 2 * m16 + h;
      int gs = 2 * m16 + 1 - h;
      unsigned int x0 = (unsigned int)__shfl_xor((int)wpk[2 * gs],     32);
      unsigned int x1 = (unsigned int)__shfl_xor((int)wpk[2 * gs + 1], 32);
      union { unsigned int u[4]; short8 s; } bu;
      bu.u[0] = h ? x0 : wpk[2 * go];
      bu.u[1] = h ? x1 : wpk[2 * go + 1];
      bu.u[2] = h ? wpk[2 * go]     : x0;
      bu.u[3] = h ? wpk[2 * go + 1] : x1;
      short8 bfrag = bu.s;
#pragma unroll
      for (int dt = 0; dt < 2; ++dt) {
        int d = dt * 32 + ql;
        int slot = (tt * 4 + m16 * 2 + h) ^ (d & 7);
        short8 vf = *(const short8*)&Vt[d * 192 + slot * 8];
        if (dt == 0)
          oacc0 = __builtin_amdgcn_mfma_f32_32x32x16_bf16(vf, bfrag, oacc0, 0, 0, 0);
        else
          oacc1 = __builtin_amdgcn_mfma_f32_32x32x16_bf16(vf, bfrag, oacc1, 0, 0, 0);
      }
    }
  }
  float lt = l + __shfl_xor(l, 32);
  lt += exp2f(sinks[head] * LOG2E - m);
  float inv = 1.f / lt;
  unsigned short* op = attn + (size_t)i_q * 4096 + head * 64;
#pragma unroll
  for (int dt = 0; dt < 2; ++dt) {
#pragma unroll
    for (int g = 0; g < 4; ++g) {
      float f0, f1, f2, f3;
      if (dt == 0) {
        f0 = oacc0[4 * g]; f1 = oacc0[4 * g + 1]; f2 = oacc0[4 * g + 2]; f3 = oacc0[4 * g + 3];
      } else {
        f0 = oacc1[4 * g]; f1 = oacc1[4 * g + 1]; f2 = oacc1[4 * g + 2]; f3 = oacc1[4 * g + 3];
      }
      unsigned int u0, u1;
      asm("v_cvt_pk_bf16_f32 %0, %1, %2" : "=v"(u0) : "v"(f0 * inv), "v"(f1 * inv));
      asm("v_cvt_pk_bf16_f32 %0, %1, %2" : "=v"(u1) : "v"(f2 * inv), "v"(f3 * inv));
      int d = dt * 32 + 8 * g + 4 * h;
      uint2 pr; pr.x = u0; pr.y = u1;
      *(uint2*)(op + d) = pr;
    }
  }
}

extern "C" void kernel_launch(void* const* d_in, const int* in_sizes, int n_in,
                              void* d_out, int out_size, void* d_ws, size_t ws_size,
                              hipStream_t stream)
{
  const float* x      = (const float*)d_in[0];
  const float* nscale = (const float*)d_in[1];
  const float* w_qkv  = (const float*)d_in[2];
  const float* b_qkv  = (const float*)d_in[3];
  const float* sinks  = (const float*)d_in[4];
  const float* w_out  = (const float*)d_in[5];
  const float* b_out  = (const float*)d_in[6];

  char* ws = (char*)d_ws;
  unsigned short* t_bf  = (unsigned short*)(ws);                 // [2048][2880] bf16
  unsigned short* wqkvT = (unsigned short*)(ws + 11796480);      // [5120][2880] bf16
  unsigned short* qkv   = (unsigned short*)(ws + 41287680);      // [2048][5120] bf16
  unsigned short* attn  = (unsigned short*)(ws + 62259200);      // [2048][4096] bf16
  unsigned short* woutT = (unsigned short*)(ws + 79036416);      // [2880][4096] bf16

  rmsnorm_kernel<<<N_TOK, 256, 0, stream>>>(x, nscale, t_bf);
  transpose_cast<<<dim3(5120 / 32, 2880 / 32), 256, 0, stream>>>(w_qkv, wqkvT, 2880, 5120, 2880);
  transpose_cast<<<dim3(2880 / 32, 4096 / 32), 256, 0, stream>>>(w_out, woutT, 4096, 2880, 4096);
  gemm8<5, 1><<<256, 512, 0, stream>>>(t_bf, wqkvT, b_qkv, nullptr, (void*)qkv, 2880, 5120);
  rope_kernel<<<dim3(9, N_TOK), 256, 0, stream>>>(qkv);
  attn_kernel<<<dim3(64, 8), 512, 0, stream>>>(qkv, sinks, attn);
  gemm8<3, 2><<<240, 512, 0, stream>>>(attn, woutT, b_out, x, d_out, 4096, 2880);
}